// Round 1
// baseline (127.257 us; speedup 1.0000x reference)
//
#include <hip/hip_runtime.h>
#include <hip/hip_bf16.h>

#define NTOK 128
#define CHN  512
#define KTOT 1024
#define EPSV 1e-5f

typedef __attribute__((ext_vector_type(8))) short bf16x8;
typedef __attribute__((ext_vector_type(4))) float f32x4;
typedef __attribute__((ext_vector_type(2))) float f32x2;

union BfPack4 { ushort4 u; __hip_bfloat16 h[4]; };

// ws layout (bytes):
//   0        : xT   fp32 [16][512][128]   4 MB
//   4  MB    : part fp32 [4][16][128][128] 4 MB (region reserves 8 MB)
//   12 MB    : hb   bf16 [2048][1024]     4 MB
//   16 MB    : wfb  bf16 [512][1024]      1 MB
//   17 MB    : Wbf  bf16 [16][128][128]   512 KB
//   17.5 MB  : xTbf bf16 [16][512][128]   2 MB

// ---------------------------------------------------------------------------
// K0: per block (b, jt, ct): transpose a 64x64 tile of x into xT (fp32+bf16)
//     and emit bf16 x rows into hb-left. 256 blocks x 256 thr.
// ---------------------------------------------------------------------------
__global__ __launch_bounds__(256)
void k0_transpose(const float* __restrict__ xg,
                  float* __restrict__ xT,
                  __hip_bfloat16* __restrict__ xTbf,
                  __hip_bfloat16* __restrict__ hb)
{
    __shared__ float ts[64 * 68];   // pad 68: rows 16B-aligned
    const int t  = threadIdx.x;
    const int bk = blockIdx.x;
    const int b  = bk >> 4;
    const int jt = (bk >> 3) & 1;
    const int ct = bk & 7;
    const int j0 = jt * 64, c0 = ct * 64;

    // load 64 rows x 64 cols; thread: row j0+(t>>2), 16 floats at quad*16
    const int jr = t >> 2, qd = t & 3;
    const float* src = xg + ((size_t)(b * NTOK) + j0 + jr) * CHN + c0 + qd * 16;
    float4 v0 = *(const float4*)&src[0];
    float4 v1 = *(const float4*)&src[4];
    float4 v2 = *(const float4*)&src[8];
    float4 v3 = *(const float4*)&src[12];
    *(float4*)&ts[jr * 68 + qd * 16 + 0]  = v0;
    *(float4*)&ts[jr * 68 + qd * 16 + 4]  = v1;
    *(float4*)&ts[jr * 68 + qd * 16 + 8]  = v2;
    *(float4*)&ts[jr * 68 + qd * 16 + 12] = v3;

    // hb-left bf16 from registers (row b*128+j0+jr, cols c0+qd*16..+16)
    {
        __hip_bfloat16* hrow = hb + ((size_t)(b * NTOK) + j0 + jr) * KTOT + c0 + qd * 16;
        BfPack4 p;
        p.h[0]=__float2bfloat16(v0.x); p.h[1]=__float2bfloat16(v0.y);
        p.h[2]=__float2bfloat16(v0.z); p.h[3]=__float2bfloat16(v0.w);
        *(ushort4*)&hrow[0] = p.u;
        p.h[0]=__float2bfloat16(v1.x); p.h[1]=__float2bfloat16(v1.y);
        p.h[2]=__float2bfloat16(v1.z); p.h[3]=__float2bfloat16(v1.w);
        *(ushort4*)&hrow[4] = p.u;
        p.h[0]=__float2bfloat16(v2.x); p.h[1]=__float2bfloat16(v2.y);
        p.h[2]=__float2bfloat16(v2.z); p.h[3]=__float2bfloat16(v2.w);
        *(ushort4*)&hrow[8] = p.u;
        p.h[0]=__float2bfloat16(v3.x); p.h[1]=__float2bfloat16(v3.y);
        p.h[2]=__float2bfloat16(v3.z); p.h[3]=__float2bfloat16(v3.w);
        *(ushort4*)&hrow[12] = p.u;
    }
    __syncthreads();

    // write transposed: thread: cs = t>>4 (c = cs+16m), jj = (t&15)*4
    const int cs = t >> 4, jj = (t & 15) * 4;
    #pragma unroll
    for (int m = 0; m < 4; ++m) {
        const int c = cs + 16 * m;
        float4 o;
        o.x = ts[(jj + 0) * 68 + c];
        o.y = ts[(jj + 1) * 68 + c];
        o.z = ts[(jj + 2) * 68 + c];
        o.w = ts[(jj + 3) * 68 + c];
        const size_t base = ((size_t)(b * CHN) + c0 + c) * NTOK + j0 + jj;
        *(float4*)&xT[base] = o;
        BfPack4 p;
        p.h[0]=__float2bfloat16(o.x); p.h[1]=__float2bfloat16(o.y);
        p.h[2]=__float2bfloat16(o.z); p.h[3]=__float2bfloat16(o.w);
        *(ushort4*)&xTbf[base] = p.u;
    }
}

// ---------------------------------------------------------------------------
// K1a: partial scores, packed-fp32 (v_pk_*). block = (b, i-quad, ch-slice of
// 128). 2048 blocks x 128 thr, NO LDS, NO barriers. lane j reads xT coalesced;
// xi/wd wave-uniform (s_load_dwordx2 pairs).
// part[s][b][i][j] += sum_{c in slice} |x_i,c - x_j,c| * wd_c
// ---------------------------------------------------------------------------
__global__ __launch_bounds__(128)
void k1a_scores(const float* __restrict__ xg,
                const float* __restrict__ xT,
                const float* __restrict__ wde,
                float* __restrict__ part)
{
    const int bk = blockIdx.x;
    const int s  = bk & 3;
    const int iq = (bk >> 2) & 31;
    const int b  = bk >> 7;
    const int i0 = iq * 4;
    const int c0 = s * 128;
    const int j  = threadIdx.x;

    const float* __restrict__ xtp = xT + ((size_t)(b * CHN) + c0) * NTOK + j;
    const float* __restrict__ xip = xg + ((size_t)(b * NTOK) + i0) * CHN + c0;
    const float* __restrict__ wdp = wde + c0;

    f32x2 acc0 = {0.f, 0.f};
    f32x2 acc1 = acc0, acc2 = acc0, acc3 = acc0;

    #pragma unroll 2
    for (int cc = 0; cc < 128; cc += 8) {
        float xj[8];
        #pragma unroll
        for (int k = 0; k < 8; ++k) xj[k] = xtp[(cc + k) * NTOK];
        #pragma unroll
        for (int kp = 0; kp < 4; ++kp) {
            const int c = cc + 2 * kp;
            const f32x2 wd2 = *(const f32x2*)(wdp + c);          // uniform -> s_load_x2
            const f32x2 xiA = *(const f32x2*)(xip + 0 * CHN + c);
            const f32x2 xiB = *(const f32x2*)(xip + 1 * CHN + c);
            const f32x2 xiC = *(const f32x2*)(xip + 2 * CHN + c);
            const f32x2 xiD = *(const f32x2*)(xip + 3 * CHN + c);
            const f32x2 xj2 = { xj[2 * kp], xj[2 * kp + 1] };
            acc0 += __builtin_elementwise_abs(xiA - xj2) * wd2;  // pk_sub/and/pk_fma
            acc1 += __builtin_elementwise_abs(xiB - xj2) * wd2;
            acc2 += __builtin_elementwise_abs(xiC - xj2) * wd2;
            acc3 += __builtin_elementwise_abs(xiD - xj2) * wd2;
        }
    }

    float* pp = part + ((size_t)s * 16 + b) * (NTOK * NTOK) + (size_t)i0 * NTOK + j;
    pp[0 * NTOK] = acc0.x + acc0.y;
    pp[1 * NTOK] = acc1.x + acc1.y;
    pp[2 * NTOK] = acc2.x + acc2.y;
    pp[3 * NTOK] = acc3.x + acc3.y;
}

// ---------------------------------------------------------------------------
// K1b: softmax per row. 1024 blocks x 128 thr; wave w owns row i0+w.
// lane l handles j=l and j=l+64. Butterfly-only, no LDS, no barriers.
// Sums 4 slices (was 8).
// ---------------------------------------------------------------------------
__global__ __launch_bounds__(128)
void k1b_softmax(const float* __restrict__ part,
                 const float* __restrict__ bn_e_g,
                 const float* __restrict__ bn_e_v,
                 __hip_bfloat16* __restrict__ Wbf)
{
    const int bk = blockIdx.x;
    const int b  = bk >> 6;
    const int i  = (bk & 63) * 2 + (threadIdx.x >> 6);
    const int l  = threadIdx.x & 63;

    const float* pp = part + (size_t)(b * NTOK + i) * NTOK;
    float p1 = 0.f, p2 = 0.f;
    #pragma unroll
    for (int s = 0; s < 4; ++s) {
        p1 += pp[(size_t)s * 16 * NTOK * NTOK + l];
        p2 += pp[(size_t)s * 16 * NTOK * NTOK + l + 64];
    }
    const float sc = bn_e_g[0] * rsqrtf(bn_e_v[0] + EPSV);
    float l1 = p1 * sc - (l == i ? 1e8f : 0.f);
    float l2 = p2 * sc - (l + 64 == i ? 1e8f : 0.f);

    float m = fmaxf(l1, l2);
    #pragma unroll
    for (int off = 32; off > 0; off >>= 1) m = fmaxf(m, __shfl_xor(m, off));
    const float e1 = __expf(l1 - m);
    const float e2 = __expf(l2 - m);
    float ssum = e1 + e2;
    #pragma unroll
    for (int off = 32; off > 0; off >>= 1) ssum += __shfl_xor(ssum, off);
    const float inv = 1.f / ssum;

    __hip_bfloat16* wr = Wbf + (size_t)(b * NTOK + i) * NTOK;
    wr[l]      = __float2bfloat16(e1 * inv);
    wr[l + 64] = __float2bfloat16(e2 * inv);
}

// ---------------------------------------------------------------------------
// K1c: xnb = W @ x via bf16 MFMA -> hb right half; also converts Wf -> bf16.
// 512 blocks x 256 thr. Block: (b, i-tile 32, c-tile 64), K = 128 (j).
// ---------------------------------------------------------------------------
__global__ __launch_bounds__(256)
void k1c_xnb(const __hip_bfloat16* __restrict__ Wbf,
             const __hip_bfloat16* __restrict__ xTbf,
             const float* __restrict__ wf,
             __hip_bfloat16* __restrict__ hb,
             __hip_bfloat16* __restrict__ wfb)
{
    const int bk = blockIdx.x;
    const int t  = threadIdx.x;

    // Wf row bk -> bf16 (independent of the GEMM below)
    {
        const float* wr = wf + (size_t)bk * KTOT;
        float4 u = *(const float4*)&wr[t * 4];
        BfPack4 p;
        p.h[0]=__float2bfloat16(u.x); p.h[1]=__float2bfloat16(u.y);
        p.h[2]=__float2bfloat16(u.z); p.h[3]=__float2bfloat16(u.w);
        *(ushort4*)&wfb[(size_t)bk * KTOT + t * 4] = p.u;
    }

    const int b  = bk >> 5;
    const int mt = (bk >> 3) & 3;     // i-tile of 32
    const int ct = bk & 7;            // c-tile of 64
    const int i0 = mt * 32, c0 = ct * 64;

    const int w    = t >> 6;
    const int lane = t & 63;
    const int wm   = w & 1;           // 16-row half
    const int wn   = w >> 1;          // 32-col half
    const int m16  = lane & 15;
    const int q    = lane >> 4;

    const short* A0 = (const short*)Wbf  + (size_t)(b * NTOK + i0 + wm * 16 + m16) * NTOK + q * 8;
    const short* B0 = (const short*)xTbf + ((size_t)(b * CHN) + c0 + wn * 32 + m16) * NTOK + q * 8;

    f32x4 acc0 = {0.f, 0.f, 0.f, 0.f};
    f32x4 acc1 = acc0;

    #pragma unroll
    for (int k0 = 0; k0 < NTOK; k0 += 32) {
        const bf16x8 a  = *(const bf16x8*)(A0 + k0);
        const bf16x8 b0 = *(const bf16x8*)(B0 + k0);
        const bf16x8 b1 = *(const bf16x8*)(B0 + 16 * NTOK + k0);
        acc0 = __builtin_amdgcn_mfma_f32_16x16x32_bf16(a, b0, acc0, 0, 0, 0);
        acc1 = __builtin_amdgcn_mfma_f32_16x16x32_bf16(a, b1, acc1, 0, 0, 0);
    }

    // D layout: col = lane&15 (-> c), row = q*4+r (-> i)  [verified pattern]
    #pragma unroll
    for (int ni = 0; ni < 2; ++ni) {
        const int c = c0 + wn * 32 + ni * 16 + m16;
        const f32x4 ac = ni ? acc1 : acc0;
        #pragma unroll
        for (int r = 0; r < 4; ++r) {
            const int i = i0 + wm * 16 + q * 4 + r;
            hb[(size_t)(b * NTOK + i) * KTOT + CHN + c] = __float2bfloat16(ac[r]);
        }
    }
}

// ---------------------------------------------------------------------------
// K2: out = relu(BN([x|xnb] @ Wf^T + bias)) via bf16 MFMA.
// 256 blocks x 512 thr (8 waves: 4 row-quarters x 2 col-halves, 16x32/wave).
// Was 256 thr = 1 wave/SIMD; now 2 waves/SIMD for load-latency hiding.
// ---------------------------------------------------------------------------
__global__ __launch_bounds__(512)
void k2_gemm_bn_relu(const __hip_bfloat16* __restrict__ hbp,
                     const __hip_bfloat16* __restrict__ wfbp,
                     const float* __restrict__ fb,
                     const float* __restrict__ gg,
                     const float* __restrict__ bb,
                     const float* __restrict__ mm,
                     const float* __restrict__ vv,
                     float* __restrict__ out)
{
    const int blk  = blockIdx.x;
    const int r0   = (blk >> 3) << 6;
    const int c0   = (blk & 7) << 6;
    const int t    = threadIdx.x;
    const int w    = t >> 6;
    const int lane = t & 63;
    const int wm   = w & 3;           // row quarter (16 rows)
    const int wn   = w >> 2;          // col half (32 cols)
    const int m16  = lane & 15;
    const int qq   = lane >> 4;

    const short* A0 = (const short*)hbp  + (size_t)(r0 + wm * 16 + m16) * KTOT + qq * 8;
    const short* B0 = (const short*)wfbp + (size_t)(c0 + wn * 32 + m16) * KTOT + qq * 8;

    f32x4 acc0 = {0.f, 0.f, 0.f, 0.f};
    f32x4 acc1 = acc0;

    #pragma unroll 8
    for (int k0 = 0; k0 < KTOT; k0 += 32) {
        const bf16x8 aA = *(const bf16x8*)(A0 + k0);
        const bf16x8 bA = *(const bf16x8*)(B0 + k0);
        const bf16x8 bB = *(const bf16x8*)(B0 + 16 * KTOT + k0);
        acc0 = __builtin_amdgcn_mfma_f32_16x16x32_bf16(aA, bA, acc0, 0, 0, 0);
        acc1 = __builtin_amdgcn_mfma_f32_16x16x32_bf16(aA, bB, acc1, 0, 0, 0);
    }

    #pragma unroll
    for (int ni = 0; ni < 2; ++ni) {
        const int c = c0 + wn * 32 + ni * 16 + m16;
        const float gf = gg[c] * rsqrtf(vv[c] + EPSV);
        const float ad = fb[c] - mm[c];
        const float bv = bb[c];
        const f32x4 ac = ni ? acc1 : acc0;
        #pragma unroll
        for (int r2 = 0; r2 < 4; ++r2) {
            const int row = r0 + wm * 16 + qq * 4 + r2;
            const float val = (ac[r2] + ad) * gf + bv;
            out[(size_t)row * CHN + c] = fmaxf(val, 0.f);
        }
    }
}

extern "C" void kernel_launch(void* const* d_in, const int* in_sizes, int n_in,
                              void* d_out, int out_size, void* d_ws, size_t ws_size,
                              hipStream_t stream) {
    const float* x        = (const float*)d_in[0];
    // d_in[1] = y          : unused (softmax shift-invariance)
    const float* conv_e_w = (const float*)d_in[2];
    // d_in[3] = conv_e_b   : unused (shift)
    const float* bn_e_g   = (const float*)d_in[4];
    // d_in[5,6] bn_e_b, bn_e_m : unused (shift)
    const float* bn_e_v   = (const float*)d_in[7];
    const float* conv_f_w = (const float*)d_in[8];
    const float* conv_f_b = (const float*)d_in[9];
    const float* bn_f_g   = (const float*)d_in[10];
    const float* bn_f_b   = (const float*)d_in[11];
    const float* bn_f_m   = (const float*)d_in[12];
    const float* bn_f_v   = (const float*)d_in[13];
    float* out = (float*)d_out;

    char* ws = (char*)d_ws;
    float*           xT   = (float*)(ws);                               // 4 MB
    float*           part = (float*)(ws + (4u << 20));                  // 4 MB used
    __hip_bfloat16*  hb   = (__hip_bfloat16*)(ws + (12u << 20));        // 4 MB
    __hip_bfloat16*  wfb  = (__hip_bfloat16*)(ws + (16u << 20));        // 1 MB
    __hip_bfloat16*  Wbf  = (__hip_bfloat16*)(ws + (17u << 20));        // 512 KB
    __hip_bfloat16*  xTbf = (__hip_bfloat16*)(ws + (17u << 20) + (512u << 10)); // 2 MB

    k0_transpose<<<256, 256, 0, stream>>>(x, xT, xTbf, hb);
    k1a_scores<<<2048, 128, 0, stream>>>(x, xT, conv_e_w, part);
    k1b_softmax<<<1024, 128, 0, stream>>>(part, bn_e_g, bn_e_v, Wbf);
    k1c_xnb<<<512, 256, 0, stream>>>(Wbf, xTbf, conv_f_w, hb, wfb);
    k2_gemm_bn_relu<<<256, 512, 0, stream>>>(hb, wfb, conv_f_b, bn_f_g, bn_f_b,
                                             bn_f_m, bn_f_v, out);
}

// Round 2
// 120.397 us; speedup vs baseline: 1.0570x; 1.0570x over previous
//
#include <hip/hip_runtime.h>
#include <hip/hip_bf16.h>

#define NTOK 128
#define CHN  512
#define KTOT 1024
#define EPSV 1e-5f

typedef __attribute__((ext_vector_type(8))) short bf16x8;
typedef __attribute__((ext_vector_type(4))) float f32x4;

union BfPack4 { ushort4 u; __hip_bfloat16 h[4]; };

// ws layout (bytes):
//   0        : xT   fp32 [16][512][128]   4 MB
//   12 MB    : hb   bf16 [2048][1024]     4 MB
//   16 MB    : wfb  bf16 [512][1024]      1 MB
//   17.5 MB  : xTbf bf16 [16][512][128]   2 MB

// ---------------------------------------------------------------------------
// K0: per block (b, jt, ct): transpose a 64x64 tile of x into xT (fp32+bf16)
//     and emit bf16 x rows into hb-left. Also converts 2 rows of Wf -> bf16.
//     256 blocks x 256 thr.
// ---------------------------------------------------------------------------
__global__ __launch_bounds__(256)
void k0_transpose(const float* __restrict__ xg,
                  float* __restrict__ xT,
                  __hip_bfloat16* __restrict__ xTbf,
                  __hip_bfloat16* __restrict__ hb,
                  const float* __restrict__ wf,
                  __hip_bfloat16* __restrict__ wfb)
{
    __shared__ float ts[64 * 68];   // pad 68: rows 16B-aligned
    const int t  = threadIdx.x;
    const int bk = blockIdx.x;
    const int b  = bk >> 4;
    const int jt = (bk >> 3) & 1;
    const int ct = bk & 7;
    const int j0 = jt * 64, c0 = ct * 64;

    // load 64 rows x 64 cols; thread: row j0+(t>>2), 16 floats at quad*16
    const int jr = t >> 2, qd = t & 3;
    const float* src = xg + ((size_t)(b * NTOK) + j0 + jr) * CHN + c0 + qd * 16;
    float4 v0 = *(const float4*)&src[0];
    float4 v1 = *(const float4*)&src[4];
    float4 v2 = *(const float4*)&src[8];
    float4 v3 = *(const float4*)&src[12];
    *(float4*)&ts[jr * 68 + qd * 16 + 0]  = v0;
    *(float4*)&ts[jr * 68 + qd * 16 + 4]  = v1;
    *(float4*)&ts[jr * 68 + qd * 16 + 8]  = v2;
    *(float4*)&ts[jr * 68 + qd * 16 + 12] = v3;

    // hb-left bf16 from registers (row b*128+j0+jr, cols c0+qd*16..+16)
    {
        __hip_bfloat16* hrow = hb + ((size_t)(b * NTOK) + j0 + jr) * KTOT + c0 + qd * 16;
        BfPack4 p;
        p.h[0]=__float2bfloat16(v0.x); p.h[1]=__float2bfloat16(v0.y);
        p.h[2]=__float2bfloat16(v0.z); p.h[3]=__float2bfloat16(v0.w);
        *(ushort4*)&hrow[0] = p.u;
        p.h[0]=__float2bfloat16(v1.x); p.h[1]=__float2bfloat16(v1.y);
        p.h[2]=__float2bfloat16(v1.z); p.h[3]=__float2bfloat16(v1.w);
        *(ushort4*)&hrow[4] = p.u;
        p.h[0]=__float2bfloat16(v2.x); p.h[1]=__float2bfloat16(v2.y);
        p.h[2]=__float2bfloat16(v2.z); p.h[3]=__float2bfloat16(v2.w);
        *(ushort4*)&hrow[8] = p.u;
        p.h[0]=__float2bfloat16(v3.x); p.h[1]=__float2bfloat16(v3.y);
        p.h[2]=__float2bfloat16(v3.z); p.h[3]=__float2bfloat16(v3.w);
        *(ushort4*)&hrow[12] = p.u;
    }

    // Wf rows 2*bk, 2*bk+1 -> bf16 (independent of the transpose)
    {
        const int r   = 2 * bk + (t >> 7);
        const int col = (t & 127) * 8;
        const float* wsrc = wf + (size_t)r * KTOT + col;
        float4 u0 = *(const float4*)&wsrc[0];
        float4 u1 = *(const float4*)&wsrc[4];
        BfPack4 p;
        p.h[0]=__float2bfloat16(u0.x); p.h[1]=__float2bfloat16(u0.y);
        p.h[2]=__float2bfloat16(u0.z); p.h[3]=__float2bfloat16(u0.w);
        *(ushort4*)&wfb[(size_t)r * KTOT + col] = p.u;
        p.h[0]=__float2bfloat16(u1.x); p.h[1]=__float2bfloat16(u1.y);
        p.h[2]=__float2bfloat16(u1.z); p.h[3]=__float2bfloat16(u1.w);
        *(ushort4*)&wfb[(size_t)r * KTOT + col + 4] = p.u;
    }
    __syncthreads();

    // write transposed: thread: cs = t>>4 (c = cs+16m), jj = (t&15)*4
    const int cs = t >> 4, jj = (t & 15) * 4;
    #pragma unroll
    for (int m = 0; m < 4; ++m) {
        const int c = cs + 16 * m;
        float4 o;
        o.x = ts[(jj + 0) * 68 + c];
        o.y = ts[(jj + 1) * 68 + c];
        o.z = ts[(jj + 2) * 68 + c];
        o.w = ts[(jj + 3) * 68 + c];
        const size_t base = ((size_t)(b * CHN) + c0 + c) * NTOK + j0 + jj;
        *(float4*)&xT[base] = o;
        BfPack4 p;
        p.h[0]=__float2bfloat16(o.x); p.h[1]=__float2bfloat16(o.y);
        p.h[2]=__float2bfloat16(o.z); p.h[3]=__float2bfloat16(o.w);
        *(ushort4*)&xTbf[base] = p.u;
    }
}

// ---------------------------------------------------------------------------
// K1: fused scores + softmax + xnb. Block = (b, i-octet of 8 rows),
// 256 blocks x 512 thr (8 waves).
//  Phase 1: wave (rp,cq): rows rp*4..rp*4+3, channels cq*128..+128.
//           lane l: j = l and l+64. Partials -> LDS [4][8][128] f32.
//           (same 4-slice-of-128 summation grouping as the old part path)
//  Phase 2: wave w owns row w: sum 4 partials, butterfly softmax (k1b math),
//           W -> LDS bf16 [16][136] (rows 8..15 zeroed).
//  Phase 3: xnb = W @ x via MFMA (k1c's verified fragment mapping), A from
//           LDS, B from xTbf; writes hb right half. Rows 8..15 of D discarded.
// ---------------------------------------------------------------------------
__global__ __launch_bounds__(512)
void k1_fused(const float* __restrict__ xg,
              const float* __restrict__ xT,
              const float* __restrict__ wde,
              const float* __restrict__ bn_e_g,
              const float* __restrict__ bn_e_v,
              const __hip_bfloat16* __restrict__ xTbf,
              __hip_bfloat16* __restrict__ hb)
{
    __shared__ float        pLDS[4][8][128];     // 16 KB
    __shared__ __hip_bfloat16 Wlds[16][136];     // 4.25 KB, pad 136 vs bank conflicts

    const int t  = threadIdx.x;
    const int w  = t >> 6;
    const int l  = t & 63;
    const int bk = blockIdx.x;
    const int b  = bk >> 4;
    const int i0 = (bk & 15) * 8;

    // ---- phase 1: partial scores ----
    {
        const int rp = __builtin_amdgcn_readfirstlane(w >> 2);   // 0..1 (row-pair group of 4)
        const int cq = __builtin_amdgcn_readfirstlane(w & 3);    // 0..3 (c-quarter)
        const int c0 = cq * 128;
        const int r0 = rp * 4;

        const float* __restrict__ xtp = xT + ((size_t)(b * CHN) + c0) * NTOK + l;
        const float* __restrict__ xip = xg + ((size_t)(b * NTOK) + i0 + r0) * CHN + c0;
        const float* __restrict__ wdp = wde + c0;

        float a00=0.f,a01=0.f,a10=0.f,a11=0.f,a20=0.f,a21=0.f,a30=0.f,a31=0.f;
        #pragma unroll 8
        for (int c = 0; c < 128; ++c) {
            const float xj1 = xtp[c * NTOK];
            const float xj2 = xtp[c * NTOK + 64];
            const float wd  = wdp[c];               // uniform -> SGPR
            const float xi0 = xip[0 * CHN + c];     // uniform -> SGPR
            const float xi1 = xip[1 * CHN + c];
            const float xi2 = xip[2 * CHN + c];
            const float xi3 = xip[3 * CHN + c];
            a00 += fabsf(xi0 - xj1) * wd;  a01 += fabsf(xi0 - xj2) * wd;
            a10 += fabsf(xi1 - xj1) * wd;  a11 += fabsf(xi1 - xj2) * wd;
            a20 += fabsf(xi2 - xj1) * wd;  a21 += fabsf(xi2 - xj2) * wd;
            a30 += fabsf(xi3 - xj1) * wd;  a31 += fabsf(xi3 - xj2) * wd;
        }
        pLDS[cq][r0 + 0][l] = a00;  pLDS[cq][r0 + 0][l + 64] = a01;
        pLDS[cq][r0 + 1][l] = a10;  pLDS[cq][r0 + 1][l + 64] = a11;
        pLDS[cq][r0 + 2][l] = a20;  pLDS[cq][r0 + 2][l + 64] = a21;
        pLDS[cq][r0 + 3][l] = a30;  pLDS[cq][r0 + 3][l + 64] = a31;
    }
    __syncthreads();

    // ---- phase 2: softmax, wave w -> row w ----
    {
        float p1 = pLDS[0][w][l]      + pLDS[1][w][l]
                 + pLDS[2][w][l]      + pLDS[3][w][l];
        float p2 = pLDS[0][w][l + 64] + pLDS[1][w][l + 64]
                 + pLDS[2][w][l + 64] + pLDS[3][w][l + 64];
        const float sc = bn_e_g[0] * rsqrtf(bn_e_v[0] + EPSV);
        const int ir = i0 + w;                      // global row index in [0,128)
        float l1 = p1 * sc - (l == ir ? 1e8f : 0.f);
        float l2 = p2 * sc - (l + 64 == ir ? 1e8f : 0.f);

        float m = fmaxf(l1, l2);
        #pragma unroll
        for (int off = 32; off > 0; off >>= 1) m = fmaxf(m, __shfl_xor(m, off));
        const float e1 = __expf(l1 - m);
        const float e2 = __expf(l2 - m);
        float ssum = e1 + e2;
        #pragma unroll
        for (int off = 32; off > 0; off >>= 1) ssum += __shfl_xor(ssum, off);
        const float inv = 1.f / ssum;

        Wlds[w][l]          = __float2bfloat16(e1 * inv);
        Wlds[w][l + 64]     = __float2bfloat16(e2 * inv);
        Wlds[w + 8][l]      = __float2bfloat16(0.f);   // zero pad rows 8..15
        Wlds[w + 8][l + 64] = __float2bfloat16(0.f);
    }
    __syncthreads();

    // ---- phase 3: xnb via MFMA; wave w -> c-chunk of 64 ----
    {
        const int m16 = l & 15;
        const int q   = l >> 4;

        // A fragment (k1c mapping: A row = lane&15, k = (lane>>4)*8 + e + k0)
        bf16x8 afr[4];
        #pragma unroll
        for (int kk = 0; kk < 4; ++kk)
            afr[kk] = *(const bf16x8*)&Wlds[m16][q * 8 + kk * 32];

        const int cbase = w * 64;
        #pragma unroll
        for (int ni = 0; ni < 4; ++ni) {
            const int c = cbase + ni * 16 + m16;
            const short* B0 = (const short*)xTbf + ((size_t)(b * CHN) + c) * NTOK + q * 8;
            f32x4 acc = {0.f, 0.f, 0.f, 0.f};
            #pragma unroll
            for (int kk = 0; kk < 4; ++kk) {
                const bf16x8 bfr = *(const bf16x8*)(B0 + kk * 32);
                acc = __builtin_amdgcn_mfma_f32_16x16x32_bf16(afr[kk], bfr, acc, 0, 0, 0);
            }
            // D: col = lane&15 (-> c), row = q*4+r (-> i); rows >= 8 invalid
            if (q < 2) {
                #pragma unroll
                for (int r = 0; r < 4; ++r) {
                    const int i = i0 + q * 4 + r;
                    hb[(size_t)(b * NTOK + i) * KTOT + CHN + c] = __float2bfloat16(acc[r]);
                }
            }
        }
    }
}

// ---------------------------------------------------------------------------
// K2: out = relu(BN([x|xnb] @ Wf^T + bias)) via bf16 MFMA. (round-0 verified
// config: 256 blocks x 256 thr, 32x32 per wave — lowest operand redundancy)
// ---------------------------------------------------------------------------
__global__ __launch_bounds__(256)
void k2_gemm_bn_relu(const __hip_bfloat16* __restrict__ hbp,
                     const __hip_bfloat16* __restrict__ wfbp,
                     const float* __restrict__ fb,
                     const float* __restrict__ gg,
                     const float* __restrict__ bb,
                     const float* __restrict__ mm,
                     const float* __restrict__ vv,
                     float* __restrict__ out)
{
    const int blk  = blockIdx.x;
    const int r0   = (blk >> 3) << 6;
    const int c0   = (blk & 7) << 6;
    const int t    = threadIdx.x;
    const int w    = t >> 6;
    const int lane = t & 63;
    const int wm   = w & 1;
    const int wn   = w >> 1;
    const int m16  = lane & 15;
    const int qq   = lane >> 4;

    const short* A0 = (const short*)hbp  + (size_t)(r0 + wm * 32 + m16) * KTOT + qq * 8;
    const short* B0 = (const short*)wfbp + (size_t)(c0 + wn * 32 + m16) * KTOT + qq * 8;

    f32x4 acc00 = {0.f, 0.f, 0.f, 0.f};
    f32x4 acc01 = acc00, acc10 = acc00, acc11 = acc00;

    #pragma unroll 4
    for (int k0 = 0; k0 < KTOT; k0 += 32) {
        const bf16x8 aA = *(const bf16x8*)(A0 + k0);
        const bf16x8 aB = *(const bf16x8*)(A0 + 16 * KTOT + k0);
        const bf16x8 bA = *(const bf16x8*)(B0 + k0);
        const bf16x8 bB = *(const bf16x8*)(B0 + 16 * KTOT + k0);
        acc00 = __builtin_amdgcn_mfma_f32_16x16x32_bf16(aA, bA, acc00, 0, 0, 0);
        acc01 = __builtin_amdgcn_mfma_f32_16x16x32_bf16(aA, bB, acc01, 0, 0, 0);
        acc10 = __builtin_amdgcn_mfma_f32_16x16x32_bf16(aB, bA, acc10, 0, 0, 0);
        acc11 = __builtin_amdgcn_mfma_f32_16x16x32_bf16(aB, bB, acc11, 0, 0, 0);
    }

    #pragma unroll
    for (int ni = 0; ni < 2; ++ni) {
        const int c = c0 + wn * 32 + ni * 16 + m16;
        const float gf = gg[c] * rsqrtf(vv[c] + EPSV);
        const float ad = fb[c] - mm[c];
        const float bv = bb[c];
        const f32x4 acr0 = ni ? acc01 : acc00;
        const f32x4 acr1 = ni ? acc11 : acc10;
        #pragma unroll
        for (int r2 = 0; r2 < 4; ++r2) {
            int row = r0 + wm * 32 + qq * 4 + r2;
            float val = (acr0[r2] + ad) * gf + bv;
            out[(size_t)row * CHN + c] = fmaxf(val, 0.f);
            row += 16;
            val = (acr1[r2] + ad) * gf + bv;
            out[(size_t)row * CHN + c] = fmaxf(val, 0.f);
        }
    }
}

extern "C" void kernel_launch(void* const* d_in, const int* in_sizes, int n_in,
                              void* d_out, int out_size, void* d_ws, size_t ws_size,
                              hipStream_t stream) {
    const float* x        = (const float*)d_in[0];
    // d_in[1] = y          : unused (softmax shift-invariance)
    const float* conv_e_w = (const float*)d_in[2];
    // d_in[3] = conv_e_b   : unused (shift)
    const float* bn_e_g   = (const float*)d_in[4];
    // d_in[5,6] bn_e_b, bn_e_m : unused (shift)
    const float* bn_e_v   = (const float*)d_in[7];
    const float* conv_f_w = (const float*)d_in[8];
    const float* conv_f_b = (const float*)d_in[9];
    const float* bn_f_g   = (const float*)d_in[10];
    const float* bn_f_b   = (const float*)d_in[11];
    const float* bn_f_m   = (const float*)d_in[12];
    const float* bn_f_v   = (const float*)d_in[13];
    float* out = (float*)d_out;

    char* ws = (char*)d_ws;
    float*           xT   = (float*)(ws);                               // 4 MB
    __hip_bfloat16*  hb   = (__hip_bfloat16*)(ws + (12u << 20));        // 4 MB
    __hip_bfloat16*  wfb  = (__hip_bfloat16*)(ws + (16u << 20));        // 1 MB
    __hip_bfloat16*  xTbf = (__hip_bfloat16*)(ws + (17u << 20) + (512u << 10)); // 2 MB

    k0_transpose<<<256, 256, 0, stream>>>(x, xT, xTbf, hb, conv_f_w, wfb);
    k1_fused<<<256, 512, 0, stream>>>(x, xT, conv_e_w, bn_e_g, bn_e_v, xTbf, hb);
    k2_gemm_bn_relu<<<256, 256, 0, stream>>>(hb, wfb, conv_f_b, bn_f_g, bn_f_b,
                                             bn_f_m, bn_f_v, out);
}